// Round 7
// baseline (651.093 us; speedup 1.0000x reference)
//
#include <hip/hip_runtime.h>
#include <hip/hip_bf16.h>
#include <math.h>

#define N_NODES   100000
#define N_EDGES   1600000
#define IN_FEAT   50
#define HIDDEN    64
#define N_CLASSES 41

#define SCAN_CHUNK 2048
#define SCAN_NBLK  ((N_NODES + SCAN_CHUNK - 1) / SCAN_CHUNK)   // 49 (<=64)

// bf16 helpers (RNE rounding; inputs are finite gaussians)
__device__ __forceinline__ unsigned pack_bf16(float a, float b) {
  unsigned ua = __float_as_uint(a), ub = __float_as_uint(b);
  unsigned ra = (ua + 0x7fffu + ((ua >> 16) & 1u)) >> 16;
  unsigned rb = (ub + 0x7fffu + ((ub >> 16) & 1u)) >> 16;
  return (ra & 0xffffu) | (rb << 16);
}
__device__ __forceinline__ float lo_bf(unsigned u) { return __uint_as_float(u << 16); }
__device__ __forceinline__ float hi_bf(unsigned u) { return __uint_as_float(u & 0xffff0000u); }
__device__ __forceinline__ unsigned short f2bf(float a) {
  unsigned ua = __float_as_uint(a);
  return (unsigned short)((ua + 0x7fffu + ((ua >> 16) & 1u)) >> 16);
}
__device__ __forceinline__ float bf2f(unsigned short u) {
  return __uint_as_float(((unsigned)u) << 16);
}

// ---------------------------------------------------------------------------
// Prep: pack x (f32) -> xb (bf16).  5M elems = 2.5M float2.
// ---------------------------------------------------------------------------
__global__ __launch_bounds__(256) void packx_kernel(
    const float2* __restrict__ x2, unsigned* __restrict__ xb2) {
  int i = blockIdx.x * 256 + threadIdx.x;
  if (i < N_NODES * IN_FEAT / 2) {
    float2 v = x2[i];
    xb2[i] = pack_bf16(v.x, v.y);
  }
}

// ---------------------------------------------------------------------------
// Counting-sort by dst.  Step 1: histogram of dst.
// ---------------------------------------------------------------------------
__global__ __launch_bounds__(256) void hist_kernel(
    const int* __restrict__ dst, int* __restrict__ counts) {
  int e = blockIdx.x * 256 + threadIdx.x;
  if (e < N_EDGES) atomicAdd(&counts[dst[e]], 1);
}

// Step 2a: per-chunk (2048 counts) reduction -> partial[49]
__global__ __launch_bounds__(256) void scanA_kernel(
    const int* __restrict__ counts, int* __restrict__ partial) {
  __shared__ int lds[256];
  int base = blockIdx.x * SCAN_CHUNK;
  int sum = 0;
  for (int i = threadIdx.x; i < SCAN_CHUNK; i += 256) {
    int idx = base + i;
    sum += (idx < N_NODES) ? counts[idx] : 0;
  }
  lds[threadIdx.x] = sum;
  __syncthreads();
  for (int off = 128; off >= 1; off >>= 1) {
    if (threadIdx.x < off) lds[threadIdx.x] += lds[threadIdx.x + off];
    __syncthreads();
  }
  if (threadIdx.x == 0) partial[blockIdx.x] = lds[0];
}

// Step 2b: single-wave exclusive scan of the 49 partials (in place).
__global__ __launch_bounds__(64) void scanB_kernel(
    int* __restrict__ partial, int* __restrict__ start) {
  int lane = threadIdx.x;
  int orig = (lane < SCAN_NBLK) ? partial[lane] : 0;
  int v = orig;
  for (int off = 1; off < 64; off <<= 1) {
    int t = __shfl_up(v, off);
    if (lane >= off) v += t;
  }
  if (lane < SCAN_NBLK) partial[lane] = v - orig;   // exclusive
  if (lane == 0) start[N_NODES] = N_EDGES;
}

// Step 2c: per-chunk exclusive scan + chunk offset -> start[] and cursor[].
__global__ __launch_bounds__(256) void scanC_kernel(
    const int* __restrict__ counts, const int* __restrict__ blockoff,
    int* __restrict__ start, int* __restrict__ cursor) {
  __shared__ int lds[256];
  const int PT = SCAN_CHUNK / 256;                  // 8
  int base = blockIdx.x * SCAN_CHUNK + threadIdx.x * PT;
  int c[PT];
  int tsum = 0;
#pragma unroll
  for (int k = 0; k < PT; ++k) {
    int idx = base + k;
    c[k] = (idx < N_NODES) ? counts[idx] : 0;
    tsum += c[k];
  }
  lds[threadIdx.x] = tsum;
  __syncthreads();
  for (int off = 1; off < 256; off <<= 1) {         // Hillis-Steele inclusive
    int t = (threadIdx.x >= (unsigned)off) ? lds[threadIdx.x - off] : 0;
    __syncthreads();
    lds[threadIdx.x] += t;
    __syncthreads();
  }
  int run = blockoff[blockIdx.x] + lds[threadIdx.x] - tsum;  // exclusive
#pragma unroll
  for (int k = 0; k < PT; ++k) {
    int idx = base + k;
    if (idx < N_NODES) { start[idx] = run; cursor[idx] = run; }
    run += c[k];
  }
}

// Step 3: permute edge sources into dst-grouped order.
__global__ __launch_bounds__(256) void permute_kernel(
    const int* __restrict__ src, const int* __restrict__ dst,
    int* __restrict__ cursor, int* __restrict__ sorted_src) {
  int e = blockIdx.x * 256 + threadIdx.x;
  if (e < N_EDGES) {
    int pos = atomicAdd(&cursor[dst[e]], 1);
    sorted_src[pos] = src[e];
  }
}

// ---------------------------------------------------------------------------
// Fused gather + layer 1: one wave per node (R4 structure, bf16 rows).
// idxv: one coalesced index load per 64 edges, __shfl broadcast, 8 row loads
// in flight.  Rows bf16 (100 B) -> half the cache-line traffic of f32.
// ---------------------------------------------------------------------------
__global__ __launch_bounds__(256, 8) void gl1_kernel(
    const unsigned short* __restrict__ xb, const int* __restrict__ start,
    const int* __restrict__ ssrc,
    const float* __restrict__ W1l, const float* __restrict__ W1r,
    const float* __restrict__ b1, const float* __restrict__ W2l,
    float* __restrict__ h, unsigned short* __restrict__ hlb) {
  __shared__ unsigned sW1l[25 * 64];   // 6.25 KB  (k-pairs x 64 cols)
  __shared__ unsigned sW1r[25 * 64];   // 6.25 KB
  __shared__ unsigned sW2l[32 * 64];   // 8 KB (cols padded 41->64)
  int tid = threadIdx.x;
  for (int i = tid; i < 25 * 64; i += 256) {
    int p = i >> 6, c = i & 63;
    sW1l[i] = pack_bf16(W1l[(2 * p) * HIDDEN + c], W1l[(2 * p + 1) * HIDDEN + c]);
    sW1r[i] = pack_bf16(W1r[(2 * p) * HIDDEN + c], W1r[(2 * p + 1) * HIDDEN + c]);
  }
  for (int i = tid; i < 32 * 64; i += 256) {
    int p = i >> 6, c = i & 63;
    float w0 = (c < N_CLASSES) ? W2l[(2 * p) * N_CLASSES + c] : 0.f;
    float w1 = (c < N_CLASSES) ? W2l[(2 * p + 1) * N_CLASSES + c] : 0.f;
    sW2l[i] = pack_bf16(w0, w1);
  }
  __syncthreads();

  int node = (blockIdx.x * 256 + tid) >> 6;
  if (node >= N_NODES) return;
  int lane = tid & 63;
  bool fOK = (lane < IN_FEAT);

  // own row (independent load, issued early)
  float xv = fOK ? bf2f(xb[node * IN_FEAT + lane]) : 0.f;

  int s0 = start[node], s1 = start[node + 1];
  float a0 = 0.f, a1 = 0.f, a2 = 0.f, a3 = 0.f;

  for (int base = s0; base < s1; base += 64) {
    int cnt = s1 - base;
    if (cnt > 64) cnt = 64;
    // one coalesced index load for up to 64 edges
    int idxv = (lane < cnt) ? ssrc[base + lane] : 0;
    int j = 0;
    for (; j + 8 <= cnt; j += 8) {
      int i0 = __shfl(idxv, j + 0);
      int i1 = __shfl(idxv, j + 1);
      int i2 = __shfl(idxv, j + 2);
      int i3 = __shfl(idxv, j + 3);
      int i4 = __shfl(idxv, j + 4);
      int i5 = __shfl(idxv, j + 5);
      int i6 = __shfl(idxv, j + 6);
      int i7 = __shfl(idxv, j + 7);
      if (fOK) {
        float v0 = bf2f(xb[i0 * IN_FEAT + lane]);
        float v1 = bf2f(xb[i1 * IN_FEAT + lane]);
        float v2 = bf2f(xb[i2 * IN_FEAT + lane]);
        float v3 = bf2f(xb[i3 * IN_FEAT + lane]);
        float v4 = bf2f(xb[i4 * IN_FEAT + lane]);
        float v5 = bf2f(xb[i5 * IN_FEAT + lane]);
        float v6 = bf2f(xb[i6 * IN_FEAT + lane]);
        float v7 = bf2f(xb[i7 * IN_FEAT + lane]);
        a0 += v0; a1 += v1; a2 += v2; a3 += v3;
        a0 += v4; a1 += v5; a2 += v6; a3 += v7;
      }
    }
    for (; j < cnt; ++j) {
      int i0 = __shfl(idxv, j);
      if (fOK) a0 += bf2f(xb[i0 * IN_FEAT + lane]);
    }
  }
  float aggv = (a0 + a1) + (a2 + a3);

  float acc = b1[lane];
#pragma unroll
  for (int p = 0; p < 25; ++p) {
    unsigned ul = sW1l[p * 64 + lane];
    unsigned ur = sW1r[p * 64 + lane];
    float g0 = __shfl(aggv, 2 * p), g1 = __shfl(aggv, 2 * p + 1);
    float x0 = __shfl(xv, 2 * p),  x1 = __shfl(xv, 2 * p + 1);
    acc = fmaf(g0, lo_bf(ul), acc);
    acc = fmaf(g1, hi_bf(ul), acc);
    acc = fmaf(x0, lo_bf(ur), acc);
    acc = fmaf(x1, hi_bf(ur), acc);
  }
  float hval = fmaxf(acc, 0.0f);
  h[node * HIDDEN + lane] = hval;

  float acc2 = 0.0f;
#pragma unroll
  for (int p = 0; p < 32; ++p) {
    unsigned u = sW2l[p * 64 + lane];
    float h0 = __shfl(hval, 2 * p), h1 = __shfl(hval, 2 * p + 1);
    acc2 = fmaf(h0, lo_bf(u), acc2);
    acc2 = fmaf(h1, hi_bf(u), acc2);
  }
  if (lane < N_CLASSES) hlb[node * N_CLASSES + lane] = f2bf(acc2);
}

// ---------------------------------------------------------------------------
// Fused gather + layer 2 + log_softmax: one wave per node, bf16 hl rows.
// ---------------------------------------------------------------------------
__global__ __launch_bounds__(256, 8) void gfin_kernel(
    const float* __restrict__ h, const unsigned short* __restrict__ hlb,
    const int* __restrict__ start, const int* __restrict__ ssrc,
    const float* __restrict__ W2r, const float* __restrict__ b2,
    float* __restrict__ out) {
  __shared__ unsigned sW2r[32 * 64];   // 8 KB (cols padded 41->64)
  int tid = threadIdx.x;
  for (int i = tid; i < 32 * 64; i += 256) {
    int p = i >> 6, c = i & 63;
    float w0 = (c < N_CLASSES) ? W2r[(2 * p) * N_CLASSES + c] : 0.f;
    float w1 = (c < N_CLASSES) ? W2r[(2 * p + 1) * N_CLASSES + c] : 0.f;
    sW2r[i] = pack_bf16(w0, w1);
  }
  __syncthreads();

  int node = (blockIdx.x * 256 + tid) >> 6;
  if (node >= N_NODES) return;
  int lane = tid & 63;
  bool cOK = (lane < N_CLASSES);

  float hv = h[node * HIDDEN + lane];   // full-wave load, issued early

  int s0 = start[node], s1 = start[node + 1];
  float a0 = 0.f, a1 = 0.f, a2 = 0.f, a3 = 0.f;

  for (int base = s0; base < s1; base += 64) {
    int cnt = s1 - base;
    if (cnt > 64) cnt = 64;
    int idxv = (lane < cnt) ? ssrc[base + lane] : 0;
    int j = 0;
    for (; j + 8 <= cnt; j += 8) {
      int i0 = __shfl(idxv, j + 0);
      int i1 = __shfl(idxv, j + 1);
      int i2 = __shfl(idxv, j + 2);
      int i3 = __shfl(idxv, j + 3);
      int i4 = __shfl(idxv, j + 4);
      int i5 = __shfl(idxv, j + 5);
      int i6 = __shfl(idxv, j + 6);
      int i7 = __shfl(idxv, j + 7);
      if (cOK) {
        float v0 = bf2f(hlb[i0 * N_CLASSES + lane]);
        float v1 = bf2f(hlb[i1 * N_CLASSES + lane]);
        float v2 = bf2f(hlb[i2 * N_CLASSES + lane]);
        float v3 = bf2f(hlb[i3 * N_CLASSES + lane]);
        float v4 = bf2f(hlb[i4 * N_CLASSES + lane]);
        float v5 = bf2f(hlb[i5 * N_CLASSES + lane]);
        float v6 = bf2f(hlb[i6 * N_CLASSES + lane]);
        float v7 = bf2f(hlb[i7 * N_CLASSES + lane]);
        a0 += v0; a1 += v1; a2 += v2; a3 += v3;
        a0 += v4; a1 += v5; a2 += v6; a3 += v7;
      }
    }
    for (; j < cnt; ++j) {
      int i0 = __shfl(idxv, j);
      if (cOK) a0 += bf2f(hlb[i0 * N_CLASSES + lane]);
    }
  }

  float o = 0.0f;
  if (cOK) o = (a0 + a1) + (a2 + a3) + b2[lane];
#pragma unroll
  for (int p = 0; p < 32; ++p) {
    unsigned u = sW2r[p * 64 + lane];
    float h0 = __shfl(hv, 2 * p), h1 = __shfl(hv, 2 * p + 1);
    o = fmaf(h0, lo_bf(u), o);
    o = fmaf(h1, hi_bf(u), o);
  }

  float v = cOK ? o : -INFINITY;
#pragma unroll
  for (int off = 32; off >= 1; off >>= 1) v = fmaxf(v, __shfl_xor(v, off));
  float ex = cOK ? expf(o - v) : 0.0f;
  float s = ex;
#pragma unroll
  for (int off = 32; off >= 1; off >>= 1) s += __shfl_xor(s, off);
  float lse = logf(s);
  if (cOK) out[node * N_CLASSES + lane] = o - v - lse;
}

// ---------------------------------------------------------------------------
extern "C" void kernel_launch(void* const* d_in, const int* in_sizes, int n_in,
                              void* d_out, int out_size, void* d_ws, size_t ws_size,
                              hipStream_t stream) {
  const float* x   = (const float*)d_in[0];
  const float* W1l = (const float*)d_in[1];
  const float* W1r = (const float*)d_in[2];
  const float* b1  = (const float*)d_in[3];
  const float* W2l = (const float*)d_in[4];
  const float* W2r = (const float*)d_in[5];
  const float* b2  = (const float*)d_in[6];
  const int*   src = (const int*)d_in[7];
  const int*   dst = (const int*)d_in[8];
  float* out = (float*)d_out;

  // workspace layout (4-byte aligned):
  //   counts[N] | start[N+1] | cursor[N] | partial[64] | ssrc[E]
  //   | h[N*64] f32 | xb[N*50] bf16 | hlb[N*41] bf16    (~51.5 MB total)
  int* counts = (int*)d_ws;
  int* start  = counts + N_NODES;
  int* cursor = start + (N_NODES + 1);
  int* partial = cursor + N_NODES;
  int* ssrc   = partial + 64;
  float* h    = (float*)(ssrc + N_EDGES);
  unsigned short* xb  = (unsigned short*)(h + (size_t)N_NODES * HIDDEN);
  unsigned short* hlb = xb + (size_t)N_NODES * IN_FEAT;

  hipMemsetAsync(counts, 0, (size_t)N_NODES * sizeof(int), stream);

  packx_kernel<<<(N_NODES * IN_FEAT / 2 + 255) / 256, 256, 0, stream>>>(
      (const float2*)x, (unsigned*)xb);
  hist_kernel<<<(N_EDGES + 255) / 256, 256, 0, stream>>>(dst, counts);
  scanA_kernel<<<SCAN_NBLK, 256, 0, stream>>>(counts, partial);
  scanB_kernel<<<1, 64, 0, stream>>>(partial, start);
  scanC_kernel<<<SCAN_NBLK, 256, 0, stream>>>(counts, partial, start, cursor);
  permute_kernel<<<(N_EDGES + 255) / 256, 256, 0, stream>>>(src, dst, cursor, ssrc);

  int gblocks = (N_NODES * 64 + 255) / 256;   // one wave per node
  gl1_kernel<<<gblocks, 256, 0, stream>>>(xb, start, ssrc, W1l, W1r, b1, W2l, h, hlb);
  gfin_kernel<<<gblocks, 256, 0, stream>>>(h, hlb, start, ssrc, W2r, b2, out);
}

// Round 8
// 436.870 us; speedup vs baseline: 1.4904x; 1.4904x over previous
//
#include <hip/hip_runtime.h>
#include <hip/hip_bf16.h>
#include <math.h>

#define N_NODES   100000
#define N_EDGES   1600000
#define IN_FEAT   50
#define HIDDEN    64
#define N_CLASSES 41
#define NC48      48          // padded class width
#define N_TILES   (N_NODES / 16)   // 6250 exactly

#define SCAN_CHUNK 2048
#define SCAN_NBLK  ((N_NODES + SCAN_CHUNK - 1) / SCAN_CHUNK)   // 49 (<=64)

typedef __attribute__((ext_vector_type(8))) _Float16 half8;
typedef __attribute__((ext_vector_type(4))) float   float4v;

// ---------------------------------------------------------------------------
// Prep A: x (f32 [N][50]) -> xh (f16 [N][64], k-padded with zeros)
// ---------------------------------------------------------------------------
__global__ __launch_bounds__(256) void packx_kernel(
    const float* __restrict__ x, _Float16* __restrict__ xh) {
  int i = blockIdx.x * 256 + threadIdx.x;
  if (i >= N_NODES * 64) return;
  int node = i >> 6, c = i & 63;
  xh[i] = (c < IN_FEAT) ? (_Float16)x[node * IN_FEAT + c] : (_Float16)0.f;
}

// ---------------------------------------------------------------------------
// Prep B: pack transposed f16-pair weights for MFMA B-fragments.
//   wt1l/wt1r: [64 n][32 kp]  from W1l/W1r [50][64]  (k>=50 zero)
//   wt2l/wt2r: [48 n][32 kp]  from W2l/W2r [64][41]  (n>=41 zero)
// Pair kp holds k=2kp (lo half) and k=2kp+1 (hi half).
// ---------------------------------------------------------------------------
__global__ __launch_bounds__(256) void packwts_kernel(
    const float* __restrict__ W1l, const float* __restrict__ W1r,
    const float* __restrict__ W2l, const float* __restrict__ W2r,
    unsigned* __restrict__ wt1l, unsigned* __restrict__ wt1r,
    unsigned* __restrict__ wt2l, unsigned* __restrict__ wt2r) {
  int i = blockIdx.x * 256 + threadIdx.x;
  union { _Float16 h[2]; unsigned u; } pk;
  if (i < 2048 * 2) {                       // layer-1 weights
    int which = i >> 11, j = i & 2047;
    int n = j >> 5, kp = j & 31;
    const float* W = which ? W1r : W1l;
    int k0 = 2 * kp, k1 = 2 * kp + 1;
    pk.h[0] = (_Float16)((k0 < IN_FEAT) ? W[k0 * HIDDEN + n] : 0.f);
    pk.h[1] = (_Float16)((k1 < IN_FEAT) ? W[k1 * HIDDEN + n] : 0.f);
    (which ? wt1r : wt1l)[j] = pk.u;
  } else if (i < 4096 + 2 * 1536) {         // layer-2 weights
    int j = i - 4096;
    int which = (j >= 1536), jj = which ? j - 1536 : j;
    int n = jj >> 5, kp = jj & 31;
    const float* W = which ? W2r : W2l;
    pk.h[0] = (_Float16)((n < N_CLASSES) ? W[(2 * kp) * N_CLASSES + n] : 0.f);
    pk.h[1] = (_Float16)((n < N_CLASSES) ? W[(2 * kp + 1) * N_CLASSES + n] : 0.f);
    (which ? wt2r : wt2l)[jj] = pk.u;
  }
}

// ---------------------------------------------------------------------------
// Counting-sort by dst.  Step 1: histogram of dst.
// ---------------------------------------------------------------------------
__global__ __launch_bounds__(256) void hist_kernel(
    const int* __restrict__ dst, int* __restrict__ counts) {
  int e = blockIdx.x * 256 + threadIdx.x;
  if (e < N_EDGES) atomicAdd(&counts[dst[e]], 1);
}

// Step 2a: per-chunk (2048 counts) reduction -> partial[49]
__global__ __launch_bounds__(256) void scanA_kernel(
    const int* __restrict__ counts, int* __restrict__ partial) {
  __shared__ int lds[256];
  int base = blockIdx.x * SCAN_CHUNK;
  int sum = 0;
  for (int i = threadIdx.x; i < SCAN_CHUNK; i += 256) {
    int idx = base + i;
    sum += (idx < N_NODES) ? counts[idx] : 0;
  }
  lds[threadIdx.x] = sum;
  __syncthreads();
  for (int off = 128; off >= 1; off >>= 1) {
    if (threadIdx.x < off) lds[threadIdx.x] += lds[threadIdx.x + off];
    __syncthreads();
  }
  if (threadIdx.x == 0) partial[blockIdx.x] = lds[0];
}

// Step 2b: single-wave exclusive scan of the 49 partials (in place).
__global__ __launch_bounds__(64) void scanB_kernel(
    int* __restrict__ partial, int* __restrict__ start) {
  int lane = threadIdx.x;
  int orig = (lane < SCAN_NBLK) ? partial[lane] : 0;
  int v = orig;
  for (int off = 1; off < 64; off <<= 1) {
    int t = __shfl_up(v, off);
    if (lane >= off) v += t;
  }
  if (lane < SCAN_NBLK) partial[lane] = v - orig;   // exclusive
  if (lane == 0) start[N_NODES] = N_EDGES;
}

// Step 2c: per-chunk exclusive scan + chunk offset -> start[] and cursor[].
__global__ __launch_bounds__(256) void scanC_kernel(
    const int* __restrict__ counts, const int* __restrict__ blockoff,
    int* __restrict__ start, int* __restrict__ cursor) {
  __shared__ int lds[256];
  const int PT = SCAN_CHUNK / 256;                  // 8
  int base = blockIdx.x * SCAN_CHUNK + threadIdx.x * PT;
  int c[PT];
  int tsum = 0;
#pragma unroll
  for (int k = 0; k < PT; ++k) {
    int idx = base + k;
    c[k] = (idx < N_NODES) ? counts[idx] : 0;
    tsum += c[k];
  }
  lds[threadIdx.x] = tsum;
  __syncthreads();
  for (int off = 1; off < 256; off <<= 1) {         // Hillis-Steele inclusive
    int t = (threadIdx.x >= (unsigned)off) ? lds[threadIdx.x - off] : 0;
    __syncthreads();
    lds[threadIdx.x] += t;
    __syncthreads();
  }
  int run = blockoff[blockIdx.x] + lds[threadIdx.x] - tsum;  // exclusive
#pragma unroll
  for (int k = 0; k < PT; ++k) {
    int idx = base + k;
    if (idx < N_NODES) { start[idx] = run; cursor[idx] = run; }
    run += c[k];
  }
}

// Step 3: permute edge sources into dst-grouped order.
__global__ __launch_bounds__(256) void permute_kernel(
    const int* __restrict__ src, const int* __restrict__ dst,
    int* __restrict__ cursor, int* __restrict__ sorted_src) {
  int e = blockIdx.x * 256 + threadIdx.x;
  if (e < N_EDGES) {
    int pos = atomicAdd(&cursor[dst[e]], 1);
    sorted_src[pos] = src[e];
  }
}

// ---------------------------------------------------------------------------
// Gather 1: one wave per node, PURE gather (no weights, no LDS block).
//   aggh[node][64] = sum over neighbors of xh[src][0..63]   (f16 rows, 128 B)
// ---------------------------------------------------------------------------
__global__ __launch_bounds__(256) void gather1_kernel(
    const _Float16* __restrict__ xh, const int* __restrict__ start,
    const int* __restrict__ ssrc, _Float16* __restrict__ aggh) {
  int node = (blockIdx.x * 256 + threadIdx.x) >> 6;
  if (node >= N_NODES) return;
  int lane = threadIdx.x & 63;

  int s0 = start[node], s1 = start[node + 1];
  float a0 = 0.f, a1 = 0.f, a2 = 0.f, a3 = 0.f;

  for (int base = s0; base < s1; base += 64) {
    int cnt = s1 - base;
    if (cnt > 64) cnt = 64;
    int idxv = (lane < cnt) ? ssrc[base + lane] : 0;
    int j = 0;
    for (; j + 8 <= cnt; j += 8) {
      int i0 = __shfl(idxv, j + 0);
      int i1 = __shfl(idxv, j + 1);
      int i2 = __shfl(idxv, j + 2);
      int i3 = __shfl(idxv, j + 3);
      int i4 = __shfl(idxv, j + 4);
      int i5 = __shfl(idxv, j + 5);
      int i6 = __shfl(idxv, j + 6);
      int i7 = __shfl(idxv, j + 7);
      float v0 = (float)xh[i0 * 64 + lane];
      float v1 = (float)xh[i1 * 64 + lane];
      float v2 = (float)xh[i2 * 64 + lane];
      float v3 = (float)xh[i3 * 64 + lane];
      float v4 = (float)xh[i4 * 64 + lane];
      float v5 = (float)xh[i5 * 64 + lane];
      float v6 = (float)xh[i6 * 64 + lane];
      float v7 = (float)xh[i7 * 64 + lane];
      a0 += v0; a1 += v1; a2 += v2; a3 += v3;
      a0 += v4; a1 += v5; a2 += v6; a3 += v7;
    }
    for (; j < cnt; ++j) {
      int i0 = __shfl(idxv, j);
      a0 += (float)xh[i0 * 64 + lane];
    }
  }
  aggh[node * 64 + lane] = (_Float16)((a0 + a1) + (a2 + a3));
}

// ---------------------------------------------------------------------------
// MLP (MFMA, f16): one wave per 16-node tile.  Computes, entirely on matrix
// cores:  h  = relu(agg@W1l + x@W1r + b1)        (internal, LDS only)
//         hl = h@W2l              -> hlh  [N][48] f16
//         op = h@W2r + b2         -> opart [N][48] f32
// Layouts (verified, guide §3): A[m=lane&15][k=quad*8+j];
// B[k=quad*8+j][n=lane&15]; D col=lane&15, row=quad*4+reg.
// ---------------------------------------------------------------------------
__global__ __launch_bounds__(256) void mlp1_kernel(
    const _Float16* __restrict__ aggh, const _Float16* __restrict__ xh,
    const unsigned* __restrict__ wt1l, const unsigned* __restrict__ wt1r,
    const unsigned* __restrict__ wt2l, const unsigned* __restrict__ wt2r,
    const float* __restrict__ b1, const float* __restrict__ b2,
    _Float16* __restrict__ hlh, float* __restrict__ opart) {
  __shared__ float sH[4][16][68];   // per-wave slice, +4 pad vs banks
  int wid = (blockIdx.x * 256 + threadIdx.x) >> 6;   // global wave id = tile
  int w = (threadIdx.x >> 6) & 3;
  int lane = threadIdx.x & 63;
  int m = lane & 15, quad = lane >> 4;
  if (wid >= N_TILES) return;
  int tile = wid;

  // A-fragments for agg and x: node = tile*16 + m, k = s*32 + quad*8 + j
  half8 Aa[2], Ax[2];
#pragma unroll
  for (int s = 0; s < 2; ++s) {
    int off = (tile * 16 + m) * 64 + s * 32 + quad * 8;
    Aa[s] = *(const half8*)(aggh + off);
    Ax[s] = *(const half8*)(xh + off);
  }

  // ---- layer 1: h tiles (4 n-tiles of 16 cols) ----
#pragma unroll
  for (int t = 0; t < 4; ++t) {
    int n = t * 16 + m;
    // B-frags: wt[n][kp], kp = s*16 + quad*4 + 0..3  (16 B each)
    half8 Bl0 = *(const half8*)(wt1l + n * 32 + quad * 4);
    half8 Bl1 = *(const half8*)(wt1l + n * 32 + 16 + quad * 4);
    half8 Br0 = *(const half8*)(wt1r + n * 32 + quad * 4);
    half8 Br1 = *(const half8*)(wt1r + n * 32 + 16 + quad * 4);
    float4v acc = {0.f, 0.f, 0.f, 0.f};
    acc = __builtin_amdgcn_mfma_f32_16x16x32_f16(Aa[0], Bl0, acc, 0, 0, 0);
    acc = __builtin_amdgcn_mfma_f32_16x16x32_f16(Aa[1], Bl1, acc, 0, 0, 0);
    acc = __builtin_amdgcn_mfma_f32_16x16x32_f16(Ax[0], Br0, acc, 0, 0, 0);
    acc = __builtin_amdgcn_mfma_f32_16x16x32_f16(Ax[1], Br1, acc, 0, 0, 0);
    float bv = b1[n];
#pragma unroll
    for (int r = 0; r < 4; ++r) {
      // D: row = quad*4 + r (node-within-tile), col = n
      sH[w][quad * 4 + r][n] = fmaxf(acc[r] + bv, 0.f);
    }
  }

  // ---- h -> A-fragments (intra-wave LDS round-trip; lockstep, no barrier)
  half8 Ah[2];
#pragma unroll
  for (int s = 0; s < 2; ++s) {
    const float* pr = &sH[w][m][s * 32 + quad * 8];
    half8 A;
#pragma unroll
    for (int jj = 0; jj < 8; ++jj) A[jj] = (_Float16)pr[jj];
    Ah[s] = A;
  }

  // ---- layer 2 (both halves): hl = h@W2l ; op = h@W2r + b2 ----
#pragma unroll
  for (int t = 0; t < 3; ++t) {
    int n = t * 16 + m;           // 0..47
    half8 Cl0 = *(const half8*)(wt2l + n * 32 + quad * 4);
    half8 Cl1 = *(const half8*)(wt2l + n * 32 + 16 + quad * 4);
    half8 Cr0 = *(const half8*)(wt2r + n * 32 + quad * 4);
    half8 Cr1 = *(const half8*)(wt2r + n * 32 + 16 + quad * 4);
    float4v acc2 = {0.f, 0.f, 0.f, 0.f};
    float4v acc3 = {0.f, 0.f, 0.f, 0.f};
    acc2 = __builtin_amdgcn_mfma_f32_16x16x32_f16(Ah[0], Cl0, acc2, 0, 0, 0);
    acc2 = __builtin_amdgcn_mfma_f32_16x16x32_f16(Ah[1], Cl1, acc2, 0, 0, 0);
    acc3 = __builtin_amdgcn_mfma_f32_16x16x32_f16(Ah[0], Cr0, acc3, 0, 0, 0);
    acc3 = __builtin_amdgcn_mfma_f32_16x16x32_f16(Ah[1], Cr1, acc3, 0, 0, 0);
    float bv = (n < N_CLASSES) ? b2[n] : 0.f;
#pragma unroll
    for (int r = 0; r < 4; ++r) {
      int row = tile * 16 + quad * 4 + r;
      hlh[row * NC48 + n] = (_Float16)acc2[r];
      opart[row * NC48 + n] = acc3[r] + bv;
    }
  }
}

// ---------------------------------------------------------------------------
// Gather 2 + softmax: one wave per node, pure gather of hl rows (f16, 96 B)
// + opart + log_softmax.  No dense math.
// ---------------------------------------------------------------------------
__global__ __launch_bounds__(256) void gather2_kernel(
    const _Float16* __restrict__ hlh, const float* __restrict__ opart,
    const int* __restrict__ start, const int* __restrict__ ssrc,
    float* __restrict__ out) {
  int node = (blockIdx.x * 256 + threadIdx.x) >> 6;
  if (node >= N_NODES) return;
  int lane = threadIdx.x & 63;
  bool gOK = (lane < NC48);          // padded cols are zeros — safe to sum
  bool cOK = (lane < N_CLASSES);

  float ov = cOK ? opart[node * NC48 + lane] : 0.f;   // early independent load

  int s0 = start[node], s1 = start[node + 1];
  float a0 = 0.f, a1 = 0.f, a2 = 0.f, a3 = 0.f;

  for (int base = s0; base < s1; base += 64) {
    int cnt = s1 - base;
    if (cnt > 64) cnt = 64;
    int idxv = (lane < cnt) ? ssrc[base + lane] : 0;
    int j = 0;
    for (; j + 8 <= cnt; j += 8) {
      int i0 = __shfl(idxv, j + 0);
      int i1 = __shfl(idxv, j + 1);
      int i2 = __shfl(idxv, j + 2);
      int i3 = __shfl(idxv, j + 3);
      int i4 = __shfl(idxv, j + 4);
      int i5 = __shfl(idxv, j + 5);
      int i6 = __shfl(idxv, j + 6);
      int i7 = __shfl(idxv, j + 7);
      if (gOK) {
        float v0 = (float)hlh[i0 * NC48 + lane];
        float v1 = (float)hlh[i1 * NC48 + lane];
        float v2 = (float)hlh[i2 * NC48 + lane];
        float v3 = (float)hlh[i3 * NC48 + lane];
        float v4 = (float)hlh[i4 * NC48 + lane];
        float v5 = (float)hlh[i5 * NC48 + lane];
        float v6 = (float)hlh[i6 * NC48 + lane];
        float v7 = (float)hlh[i7 * NC48 + lane];
        a0 += v0; a1 += v1; a2 += v2; a3 += v3;
        a0 += v4; a1 += v5; a2 += v6; a3 += v7;
      }
    }
    for (; j < cnt; ++j) {
      int i0 = __shfl(idxv, j);
      if (gOK) a0 += (float)hlh[i0 * NC48 + lane];
    }
  }

  float o = cOK ? (ov + (a0 + a1) + (a2 + a3)) : 0.f;

  float v = cOK ? o : -INFINITY;
#pragma unroll
  for (int off = 32; off >= 1; off >>= 1) v = fmaxf(v, __shfl_xor(v, off));
  float ex = cOK ? expf(o - v) : 0.0f;
  float s = ex;
#pragma unroll
  for (int off = 32; off >= 1; off >>= 1) s += __shfl_xor(s, off);
  float lse = logf(s);
  if (cOK) out[node * N_CLASSES + lane] = o - v - lse;
}

// ---------------------------------------------------------------------------
extern "C" void kernel_launch(void* const* d_in, const int* in_sizes, int n_in,
                              void* d_out, int out_size, void* d_ws, size_t ws_size,
                              hipStream_t stream) {
  const float* x   = (const float*)d_in[0];
  const float* W1l = (const float*)d_in[1];
  const float* W1r = (const float*)d_in[2];
  const float* b1  = (const float*)d_in[3];
  const float* W2l = (const float*)d_in[4];
  const float* W2r = (const float*)d_in[5];
  const float* b2  = (const float*)d_in[6];
  const int*   src = (const int*)d_in[7];
  const int*   dst = (const int*)d_in[8];
  float* out = (float*)d_out;

  // workspace layout (~62 MB):
  //   counts[N] start[N+1] cursor[N] partial[64] ssrc[E]
  //   wt1l[2048] wt1r[2048] wt2l[1536] wt2r[1536]   (u32)
  //   opart[N*48] f32 | xh[N*64] f16 | aggh[N*64] f16 | hlh[N*48] f16
  int* counts  = (int*)d_ws;
  int* start   = counts + N_NODES;
  int* cursor  = start + (N_NODES + 1);
  int* partial = cursor + N_NODES;
  int* ssrc    = partial + 64;
  unsigned* wt1l = (unsigned*)(ssrc + N_EDGES);
  unsigned* wt1r = wt1l + 2048;
  unsigned* wt2l = wt1r + 2048;
  unsigned* wt2r = wt2l + 1536;
  float* opart   = (float*)(wt2r + 1536);
  _Float16* xh   = (_Float16*)(opart + (size_t)N_NODES * NC48);
  _Float16* aggh = xh + (size_t)N_NODES * 64;
  _Float16* hlh  = aggh + (size_t)N_NODES * 64;

  hipMemsetAsync(counts, 0, (size_t)N_NODES * sizeof(int), stream);

  packx_kernel<<<(N_NODES * 64 + 255) / 256, 256, 0, stream>>>(x, xh);
  packwts_kernel<<<(7168 + 255) / 256, 256, 0, stream>>>(
      W1l, W1r, W2l, W2r, wt1l, wt1r, wt2l, wt2r);
  hist_kernel<<<(N_EDGES + 255) / 256, 256, 0, stream>>>(dst, counts);
  scanA_kernel<<<SCAN_NBLK, 256, 0, stream>>>(counts, partial);
  scanB_kernel<<<1, 64, 0, stream>>>(partial, start);
  scanC_kernel<<<SCAN_NBLK, 256, 0, stream>>>(counts, partial, start, cursor);
  permute_kernel<<<(N_EDGES + 255) / 256, 256, 0, stream>>>(src, dst, cursor, ssrc);

  int gblocks = (N_NODES * 64 + 255) / 256;   // one wave per node
  gather1_kernel<<<gblocks, 256, 0, stream>>>(xh, start, ssrc, aggh);
  mlp1_kernel<<<(N_TILES * 64 + 255) / 256, 256, 0, stream>>>(
      aggh, xh, wt1l, wt1r, wt2l, wt2r, b1, b2, hlh, opart);
  gather2_kernel<<<gblocks, 256, 0, stream>>>(hlh, opart, start, ssrc, out);
}